// Round 6
// baseline (436.628 us; speedup 1.0000x reference)
//
#include <hip/hip_runtime.h>

#define B_  2
#define NH  16
#define S_  2048
#define D_  128
#define HID 2048

typedef _Float16 half_t;
typedef _Float16 f16x8 __attribute__((ext_vector_type(8)));
typedef _Float16 f16x4_t __attribute__((ext_vector_type(4)));
typedef float f32x4 __attribute__((ext_vector_type(4)));

__device__ __forceinline__ void glds16(const half_t* g, half_t* l) {
    __builtin_amdgcn_global_load_lds(
        (const __attribute__((address_space(1))) void*)g,
        (__attribute__((address_space(3))) void*)l, 16, 0, 0);
}
__device__ __forceinline__ float fexp2(float x) { return __builtin_amdgcn_exp2f(x); }

// ---------------- fused fp32 -> fp16 convert ----------------
__global__ __launch_bounds__(256) void cvt_all(
    const float* __restrict__ x,  const float* __restrict__ wq, const float* __restrict__ wk,
    const float* __restrict__ wv, const float* __restrict__ wo, half_t* __restrict__ dst)
{
    long i = ((long)blockIdx.x * 256 + threadIdx.x) * 4;
    const float* src; long off;
    if (i < 8388608)       { src = x;  off = i; }
    else if (i < 12582912) { src = wq; off = i - 8388608; }
    else if (i < 16777216) { src = wk; off = i - 12582912; }
    else if (i < 20971520) { src = wv; off = i - 16777216; }
    else                   { src = wo; off = i - 20971520; }
    float4 v = *(const float4*)(src + off);
    f16x4_t h;
    h[0] = (half_t)v.x; h[1] = (half_t)v.y; h[2] = (half_t)v.z; h[3] = (half_t)v.w;
    *(f16x4_t*)(dst + i) = h;
}

// ---------------- fused QKV GEMM + RoPE (m97 structure, BK=64) ----------------
// BK=64: halves barrier-pair count (the m97 limiter is the vmcnt(0) drain at each
// __syncthreads), doubles MFMA per pair. 1536 blocks = 3/CU -> drains hidden by TLP.
__global__ __launch_bounds__(256, 3) void qkv_gemm(
    const half_t* __restrict__ xb,
    const half_t* __restrict__ wqb, const half_t* __restrict__ wkb, const half_t* __restrict__ wvb,
    const float* __restrict__ bq, const float* __restrict__ bk, const float* __restrict__ bv,
    const float* __restrict__ cosp, const float* __restrict__ sinp,
    half_t* __restrict__ qo, half_t* __restrict__ ko, half_t* __restrict__ vto)
{
    __shared__ __align__(16) half_t As[128 * 64];
    __shared__ __align__(16) half_t Bs[128 * 64];
    const int m0 = blockIdx.x * 128;
    const int n0 = blockIdx.y * 128;
    const int z  = blockIdx.z;
    const half_t* wb   = (z == 0) ? wqb : (z == 1) ? wkb : wvb;
    const float*  bias = (z == 0) ? bq  : (z == 1) ? bk  : bv;
    const int tid = threadIdx.x, wave = tid >> 6, lane = tid & 63;
    const int quad = lane >> 4, lrow = lane & 15;
    const int wm = wave >> 1, wn = wave & 1;

    // staging: wave w owns rows w*8+(lane>>3) (+32 per pass); lane's phys chunk = lane&7
    // logical chunk c8 = (phys - row&7)&7  (row&7 == lane>>3)
    const int sr = wave * 8 + (lane >> 3);
    const int c8 = ((lane & 7) - (lane >> 3)) & 7;
    const half_t* ag = xb + (size_t)(m0 + sr) * HID + c8 * 8;
    const half_t* bg = wb + (size_t)(n0 + sr) * HID + c8 * 8;
    half_t* alb = &As[(wave * 8) * 64];
    half_t* blb = &Bs[(wave * 8) * 64];

    f32x4 acc[4][4] = {};

    for (int k0 = 0; k0 < HID; k0 += 64) {
        __syncthreads();
#pragma unroll
        for (int p = 0; p < 4; ++p) {
            glds16(ag + k0 + (size_t)(p * 32) * HID, alb + p * 32 * 64);
            glds16(bg + k0 + (size_t)(p * 32) * HID, blb + p * 32 * 64);
        }
        __syncthreads();
#pragma unroll
        for (int ks = 0; ks < 2; ++ks) {
            f16x8 af[4], bf[4];
#pragma unroll
            for (int mt = 0; mt < 4; mt++) {
                const int ra = wm * 64 + mt * 16 + lrow;
                const int pa = (ks * 4 + quad + (ra & 7)) & 7;
                af[mt] = *(const f16x8*)&As[ra * 64 + pa * 8];
            }
#pragma unroll
            for (int nt = 0; nt < 4; nt++) {
                const int rb = wn * 16 + nt * 32 + lrow;
                const int pb = (ks * 4 + quad + (rb & 7)) & 7;
                bf[nt] = *(const f16x8*)&Bs[rb * 64 + pb * 8];
            }
#pragma unroll
            for (int mt = 0; mt < 4; mt++)
#pragma unroll
                for (int nt = 0; nt < 4; nt++)
                    acc[mt][nt] = __builtin_amdgcn_mfma_f32_16x16x32_f16(af[mt], bf[nt], acc[mt][nt], 0, 0, 0);
        }
    }

    const int head = blockIdx.y;
    float bs_[4];
#pragma unroll
    for (int nt = 0; nt < 4; nt++) bs_[nt] = bias[n0 + nt * 32 + wn * 16 + lrow];
#pragma unroll
    for (int mt = 0; mt < 4; mt++) {
#pragma unroll
        for (int r = 0; r < 4; r++) {
            const int m  = m0 + wm * 64 + mt * 16 + quad * 4 + r;
            const int bb = m >> 11;
            const int st = m & (S_ - 1);
            float res[4];
#pragma unroll
            for (int nt = 0; nt < 4; nt++) res[nt] = acc[mt][nt][r] + bs_[nt];
            if (z < 2) {
                const float* cr = cosp + st * D_;
                const float* sr2 = sinp + st * D_;
#pragma unroll
                for (int pr = 0; pr < 2; pr++) {
                    const int dlo = pr * 32 + wn * 16 + lrow;
                    float cl = cr[dlo], sl = sr2[dlo], ch = cr[dlo + 64], sh = sr2[dlo + 64];
                    float lo = res[pr], hi = res[pr + 2];
                    res[pr]     = lo * cl - hi * sl;
                    res[pr + 2] = hi * ch + lo * sh;
                }
                half_t* dst = (z == 0 ? qo : ko) + ((size_t)(bb * NH + head) * S_ + st) * D_;
#pragma unroll
                for (int nt = 0; nt < 4; nt++) dst[nt * 32 + wn * 16 + lrow] = (half_t)res[nt];
            } else {
                half_t* dst = vto + (size_t)(bb * NH + head) * D_ * S_ + st;
#pragma unroll
                for (int nt = 0; nt < 4; nt++) dst[(size_t)(nt * 32 + wn * 16 + lrow) * S_] = (half_t)res[nt];
            }
        }
    }
}

// ---------------- flash attention: Q-tile 128 (wave owns 32 rows), S^T softmax ----------------
// T14 async-STAGE (reg-staged next K/V tile, loads in flight across compute) + T5 setprio.
// Measured neutral vs glds16 form (R3 vs R5) -> kept.
#define PLD 72
__global__ __launch_bounds__(256, 2) void attn_kernel(
    const half_t* __restrict__ qb, const half_t* __restrict__ kb,
    const half_t* __restrict__ vtb, half_t* __restrict__ ob)
{
    __shared__ __align__(16) half_t ks[64 * 128];      // 16 KB swizzled
    __shared__ __align__(16) half_t vs[128 * 64];      // 16 KB swizzled
    __shared__ __align__(16) half_t ps[4 * 32 * PLD];  // 18 KB wave-private P (A-layout)
    const int head = blockIdx.y, b = blockIdx.z;
    const int bh = b * NH + head;
    const int tid = threadIdx.x, wave = tid >> 6, lane = tid & 63;
    const int quad = lane >> 4, lrow = lane & 15;
    // scale * log2(e): softmax computed in exp2 domain
    const float SC = 0.08838834764831845f * 1.4426950408889634f;
    const int q0 = blockIdx.x * 128 + wave * 32;

    // Q fragments, pre-scaled (used as MFMA *B* operand: B-frag(X) == A-frag(X) data)
    f16x8 qf[2][4];
#pragma unroll
    for (int mt = 0; mt < 2; mt++) {
        const half_t* qrow = qb + ((size_t)bh * S_ + q0 + mt * 16 + lrow) * D_;
#pragma unroll
        for (int kc = 0; kc < 4; kc++) {
            f16x8 v = *(const f16x8*)(qrow + kc * 32 + quad * 8);
#pragma unroll
            for (int j = 0; j < 8; j++) v[j] = (half_t)((float)v[j] * SC);
            qf[mt][kc] = v;
        }
    }

    const half_t* kbase = kb + (size_t)bh * S_ * D_;
    const half_t* vbase = vtb + (size_t)bh * D_ * S_;
    const int pbase = wave * 32 * PLD;

    f16x8 kreg[4], vreg[4];
    // per-stripe source addresses, EXACTLY mirroring the glds16 addressing they replace:
    // K stripe i: row rk = wave*16 + i*4 + (lane>>4), col = (((lane&15) - (rk&7))&15)*8
    // V stripe i: row rv = wave*32 + i*8 + (lane>>3), col = (((lane&7) - (rv&7))&7)*8
#define LOAD_TILE(kt_) do {                                                           \
    _Pragma("unroll")                                                                 \
    for (int i = 0; i < 4; i++) {                                                     \
        const int rk_ = wave * 16 + i * 4 + (lane >> 4);                              \
        const int ck_ = (((lane & 15) - (rk_ & 7)) & 15) * 8;                         \
        kreg[i] = *(const f16x8*)(kbase + (size_t)((kt_) * 64 + rk_) * D_ + ck_);     \
        const int rv_ = wave * 32 + i * 8 + (lane >> 3);                              \
        const int cv_ = (((lane & 7) - (rv_ & 7)) & 7) * 8;                           \
        vreg[i] = *(const f16x8*)(vbase + (size_t)rv_ * S_ + (kt_) * 64 + cv_);       \
    }                                                                                 \
} while (0)
#define WRITE_TILE() do {                                                             \
    _Pragma("unroll")                                                                 \
    for (int i = 0; i < 4; i++) {                                                     \
        *(f16x8*)&ks[(wave * 16 + i * 4) * 128 + lane * 8] = kreg[i];                 \
        *(f16x8*)&vs[(wave * 32 + i * 8) * 64  + lane * 8] = vreg[i];                 \
    }                                                                                 \
} while (0)

    float m_run[2] = {-1e30f, -1e30f}, l_run[2] = {0.f, 0.f};
    f32x4 o[2][8] = {};

    // prologue: tile 0 staged
    LOAD_TILE(0);
    WRITE_TILE();
    __syncthreads();

    for (int kt = 0; kt < 32; kt++) {
        // issue next tile's global loads now; they land during compute (T14)
        if (kt + 1 < 32) LOAD_TILE(kt + 1);

        // S^T = K_tile . Q^T : lane holds q-row = lrow, k-col = nt*16+quad*4+r  (in-lane!)
        f32x4 st[2][4] = {};
        __builtin_amdgcn_s_setprio(1);
#pragma unroll
        for (int nt = 0; nt < 4; nt++) {
            const int rk2 = nt * 16 + lrow;
#pragma unroll
            for (int kc = 0; kc < 4; kc++) {
                const int pk = (kc * 4 + quad + (rk2 & 7)) & 15;
                f16x8 kf = *(const f16x8*)&ks[rk2 * 128 + pk * 8];
                st[0][nt] = __builtin_amdgcn_mfma_f32_16x16x32_f16(kf, qf[0][kc], st[0][nt], 0, 0, 0);
                st[1][nt] = __builtin_amdgcn_mfma_f32_16x16x32_f16(kf, qf[1][kc], st[1][nt], 0, 0, 0);
            }
        }
        __builtin_amdgcn_s_setprio(0);

        // online softmax: in-lane tree + 2 shuffles; packed b64 P stores (A-layout)
        bool upd = false;
        float alpha[2];
#pragma unroll
        for (int mt = 0; mt < 2; mt++) {
            float m01 = fmaxf(fmaxf(st[mt][0][0], st[mt][0][1]), fmaxf(st[mt][0][2], st[mt][0][3]));
            float m11 = fmaxf(fmaxf(st[mt][1][0], st[mt][1][1]), fmaxf(st[mt][1][2], st[mt][1][3]));
            float m21 = fmaxf(fmaxf(st[mt][2][0], st[mt][2][1]), fmaxf(st[mt][2][2], st[mt][2][3]));
            float m31 = fmaxf(fmaxf(st[mt][3][0], st[mt][3][1]), fmaxf(st[mt][3][2], st[mt][3][3]));
            float mx = fmaxf(fmaxf(m01, m11), fmaxf(m21, m31));
            mx = fmaxf(mx, __shfl_xor(mx, 16));
            mx = fmaxf(mx, __shfl_xor(mx, 32));
            const float mnew = fmaxf(m_run[mt], mx);
            alpha[mt] = fexp2(m_run[mt] - mnew);
            upd = upd || (mnew > m_run[mt]);
            m_run[mt] = mnew;
            float rs = 0.f;
#pragma unroll
            for (int nt = 0; nt < 4; nt++) {
                f16x4_t pk4;
#pragma unroll
                for (int r = 0; r < 4; r++) {
                    float p = fexp2(st[mt][nt][r] - mnew);
                    rs += p;
                    pk4[r] = (half_t)p;
                }
                *(f16x4_t*)&ps[pbase + (mt * 16 + lrow) * PLD + nt * 16 + quad * 4] = pk4;
            }
            rs += __shfl_xor(rs, 16);
            rs += __shfl_xor(rs, 32);
            l_run[mt] = l_run[mt] * alpha[mt] + rs;
        }
        if (__any(upd)) {
#pragma unroll
            for (int mt = 0; mt < 2; mt++) {
                float ab[4];
#pragma unroll
                for (int r = 0; r < 4; r++) ab[r] = __shfl(alpha[mt], quad * 4 + r, 16);
#pragma unroll
                for (int dt = 0; dt < 8; dt++)
#pragma unroll
                    for (int r = 0; r < 4; r++) o[mt][dt][r] *= ab[r];
            }
        }

        // O += P V
        __builtin_amdgcn_s_setprio(1);
#pragma unroll
        for (int kc2 = 0; kc2 < 2; kc2++) {
            f16x8 pf0 = *(const f16x8*)&ps[pbase + lrow * PLD + kc2 * 32 + quad * 8];
            f16x8 pf1 = *(const f16x8*)&ps[pbase + (16 + lrow) * PLD + kc2 * 32 + quad * 8];
#pragma unroll
            for (int dt = 0; dt < 8; dt++) {
                const int rv2 = dt * 16 + lrow;
                const int pv = (kc2 * 4 + quad + (rv2 & 7)) & 7;
                f16x8 vf = *(const f16x8*)&vs[rv2 * 64 + pv * 8];
                o[0][dt] = __builtin_amdgcn_mfma_f32_16x16x32_f16(pf0, vf, o[0][dt], 0, 0, 0);
                o[1][dt] = __builtin_amdgcn_mfma_f32_16x16x32_f16(pf1, vf, o[1][dt], 0, 0, 0);
            }
        }
        __builtin_amdgcn_s_setprio(0);

        // stage next tile into LDS (loads have had the whole compute to land)
        __syncthreads();
        if (kt + 1 < 32) WRITE_TILE();
        __syncthreads();
    }

    // epilogue
#pragma unroll
    for (int mt = 0; mt < 2; mt++) {
        const float rl = 1.f / l_run[mt];
        float rb[4];
#pragma unroll
        for (int r = 0; r < 4; r++) rb[r] = __shfl(rl, quad * 4 + r, 16);
#pragma unroll
        for (int dt = 0; dt < 8; dt++) {
            const int d = dt * 16 + lrow;
#pragma unroll
            for (int r = 0; r < 4; r++) {
                const int row = q0 + mt * 16 + quad * 4 + r;
                ob[((size_t)b * S_ + row) * HID + head * D_ + d] = (half_t)(o[mt][dt][r] * rb[r]);
            }
        }
    }
#undef LOAD_TILE
#undef WRITE_TILE
}

// ---------------- output projection (BM=64, BK=32, 1024 blocks = 4/CU) ----------------
// out_gemm is grid-limited: at 128x128 tiles only 512 blocks = 2/CU, too little TLP to
// hide barrier drains (BK=64 regression, R3: rest +22us). 64x128 tile -> 1024 blocks,
// 4/CU co-residency; BK=32 keeps the per-barrier staging burst short. Wave owns 32x64.
__global__ __launch_bounds__(256, 4) void out_gemm(
    const half_t* __restrict__ ab, const half_t* __restrict__ wob, float* __restrict__ out)
{
    __shared__ __align__(16) half_t As[64 * 32];    // 4 KB
    __shared__ __align__(16) half_t Bs[128 * 32];   // 8 KB
    const int m0 = blockIdx.x * 64;
    const int n0 = blockIdx.y * 128;
    const int tid = threadIdx.x, wave = tid >> 6, lane = tid & 63;
    const int quad = lane >> 4, lrow = lane & 15;
    const int wm = wave >> 1, wn = wave & 1;

    // staging: wave w covers rows w*16 + (lane>>2); phys chunk = lane&3;
    // logical chunk = (phys - row>>1)&3 = ((lane&3) - (lane>>3))&3  (w*16>>1 == 0 mod 4)
    const int srow = wave * 16 + (lane >> 2);
    const int cA   = (((lane & 3) - (lane >> 3)) & 3) * 8;
    const half_t* ag  = ab  + (size_t)(m0 + srow) * HID + cA;
    const half_t* bg0 = wob + (size_t)(n0 + srow) * HID + cA;
    const half_t* bg1 = bg0 + (size_t)64 * HID;
    half_t* al  = &As[(wave * 16) * 32];
    half_t* bl0 = &Bs[(wave * 16) * 32];
    half_t* bl1 = &Bs[(64 + wave * 16) * 32];

    f32x4 acc[2][4] = {};

    for (int k0 = 0; k0 < HID; k0 += 32) {
        __syncthreads();
        glds16(ag  + k0, al);
        glds16(bg0 + k0, bl0);
        glds16(bg1 + k0, bl1);
        __syncthreads();
        f16x8 af[2], bf[4];
#pragma unroll
        for (int mt = 0; mt < 2; mt++) {
            const int ra = wm * 32 + mt * 16 + lrow;
            const int pa = (quad + (ra >> 1)) & 3;
            af[mt] = *(const f16x8*)&As[ra * 32 + pa * 8];
        }
#pragma unroll
        for (int nt = 0; nt < 4; nt++) {
            const int rb = wn * 16 + nt * 32 + lrow;
            const int pb = (quad + (rb >> 1)) & 3;
            bf[nt] = *(const f16x8*)&Bs[rb * 32 + pb * 8];
        }
#pragma unroll
        for (int mt = 0; mt < 2; mt++)
#pragma unroll
            for (int nt = 0; nt < 4; nt++)
                acc[mt][nt] = __builtin_amdgcn_mfma_f32_16x16x32_f16(af[mt], bf[nt], acc[mt][nt], 0, 0, 0);
    }

#pragma unroll
    for (int mt = 0; mt < 2; mt++)
#pragma unroll
        for (int r = 0; r < 4; r++) {
            const int m = m0 + wm * 32 + mt * 16 + quad * 4 + r;
#pragma unroll
            for (int nt = 0; nt < 4; nt++)
                out[(size_t)m * HID + n0 + nt * 32 + wn * 16 + lrow] = acc[mt][nt][r];
        }
}

extern "C" void kernel_launch(void* const* d_in, const int* in_sizes, int n_in,
                              void* d_out, int out_size, void* d_ws, size_t ws_size,
                              hipStream_t stream)
{
    const float* x    = (const float*)d_in[0];
    const float* cosp = (const float*)d_in[1];
    const float* sinp = (const float*)d_in[2];
    const float* wq   = (const float*)d_in[3];
    const float* bq   = (const float*)d_in[4];
    const float* wk   = (const float*)d_in[5];
    const float* bk   = (const float*)d_in[6];
    const float* wv   = (const float*)d_in[7];
    const float* bv   = (const float*)d_in[8];
    const float* wo   = (const float*)d_in[9];
    float* out = (float*)d_out;

    half_t* w   = (half_t*)d_ws;
    half_t* xb  = w;
    half_t* wqb = xb  + 8388608;
    half_t* wkb = wqb + 4194304;
    half_t* wvb = wkb + 4194304;
    half_t* wob = wvb + 4194304;
    half_t* qo  = wob + 4194304;        // (b,h,s,d)
    half_t* ko  = qo  + 8388608;        // (b,h,s,d)
    half_t* vto = ko  + 8388608;        // (b,h,d,s)
    half_t* ob  = vto + 8388608;        // (b,s,h*d)

    cvt_all<<<24576, 256, 0, stream>>>(x, wq, wk, wv, wo, xb);
    qkv_gemm<<<dim3(32, 16, 3), 256, 0, stream>>>(xb, wqb, wkb, wvb, bq, bk, bv,
                                                  cosp, sinp, qo, ko, vto);
    attn_kernel<<<dim3(16, 16, 2), 256, 0, stream>>>(qo, ko, vto, ob);
    out_gemm<<<dim3(64, 16), 256, 0, stream>>>(ob, wob, out);
}

// Round 7
// 407.135 us; speedup vs baseline: 1.0724x; 1.0724x over previous
//
#include <hip/hip_runtime.h>

#define B_  2
#define NH  16
#define S_  2048
#define D_  128
#define HID 2048

typedef _Float16 half_t;
typedef _Float16 f16x8 __attribute__((ext_vector_type(8)));
typedef _Float16 f16x4_t __attribute__((ext_vector_type(4)));
typedef float f32x4 __attribute__((ext_vector_type(4)));

__device__ __forceinline__ void glds16(const half_t* g, half_t* l) {
    __builtin_amdgcn_global_load_lds(
        (const __attribute__((address_space(1))) void*)g,
        (__attribute__((address_space(3))) void*)l, 16, 0, 0);
}
__device__ __forceinline__ float fexp2(float x) { return __builtin_amdgcn_exp2f(x); }

// ---------------- fused fp32 -> fp16 convert ----------------
__global__ __launch_bounds__(256) void cvt_all(
    const float* __restrict__ x,  const float* __restrict__ wq, const float* __restrict__ wk,
    const float* __restrict__ wv, const float* __restrict__ wo, half_t* __restrict__ dst)
{
    long i = ((long)blockIdx.x * 256 + threadIdx.x) * 4;
    const float* src; long off;
    if (i < 8388608)       { src = x;  off = i; }
    else if (i < 12582912) { src = wq; off = i - 8388608; }
    else if (i < 16777216) { src = wk; off = i - 12582912; }
    else if (i < 20971520) { src = wv; off = i - 16777216; }
    else                   { src = wo; off = i - 20971520; }
    float4 v = *(const float4*)(src + off);
    f16x4_t h;
    h[0] = (half_t)v.x; h[1] = (half_t)v.y; h[2] = (half_t)v.z; h[3] = (half_t)v.w;
    *(f16x4_t*)(dst + i) = h;
}

// ---------------- fused QKV GEMM + RoPE (m97 structure, BK=64) ----------------
// BK=64: halves barrier-pair count (the m97 limiter is the vmcnt(0) drain at each
// __syncthreads), doubles MFMA per pair. 1536 blocks = 3/CU -> drains hidden by TLP.
__global__ __launch_bounds__(256, 3) void qkv_gemm(
    const half_t* __restrict__ xb,
    const half_t* __restrict__ wqb, const half_t* __restrict__ wkb, const half_t* __restrict__ wvb,
    const float* __restrict__ bq, const float* __restrict__ bk, const float* __restrict__ bv,
    const float* __restrict__ cosp, const float* __restrict__ sinp,
    half_t* __restrict__ qo, half_t* __restrict__ ko, half_t* __restrict__ vto)
{
    __shared__ __align__(16) half_t As[128 * 64];
    __shared__ __align__(16) half_t Bs[128 * 64];
    const int m0 = blockIdx.x * 128;
    const int n0 = blockIdx.y * 128;
    const int z  = blockIdx.z;
    const half_t* wb   = (z == 0) ? wqb : (z == 1) ? wkb : wvb;
    const float*  bias = (z == 0) ? bq  : (z == 1) ? bk  : bv;
    const int tid = threadIdx.x, wave = tid >> 6, lane = tid & 63;
    const int quad = lane >> 4, lrow = lane & 15;
    const int wm = wave >> 1, wn = wave & 1;

    // staging: wave w owns rows w*8+(lane>>3) (+32 per pass); lane's phys chunk = lane&7
    // logical chunk c8 = (phys - row&7)&7  (row&7 == lane>>3)
    const int sr = wave * 8 + (lane >> 3);
    const int c8 = ((lane & 7) - (lane >> 3)) & 7;
    const half_t* ag = xb + (size_t)(m0 + sr) * HID + c8 * 8;
    const half_t* bg = wb + (size_t)(n0 + sr) * HID + c8 * 8;
    half_t* alb = &As[(wave * 8) * 64];
    half_t* blb = &Bs[(wave * 8) * 64];

    f32x4 acc[4][4] = {};

    for (int k0 = 0; k0 < HID; k0 += 64) {
        __syncthreads();
#pragma unroll
        for (int p = 0; p < 4; ++p) {
            glds16(ag + k0 + (size_t)(p * 32) * HID, alb + p * 32 * 64);
            glds16(bg + k0 + (size_t)(p * 32) * HID, blb + p * 32 * 64);
        }
        __syncthreads();
#pragma unroll
        for (int ks = 0; ks < 2; ++ks) {
            f16x8 af[4], bf[4];
#pragma unroll
            for (int mt = 0; mt < 4; mt++) {
                const int ra = wm * 64 + mt * 16 + lrow;
                const int pa = (ks * 4 + quad + (ra & 7)) & 7;
                af[mt] = *(const f16x8*)&As[ra * 64 + pa * 8];
            }
#pragma unroll
            for (int nt = 0; nt < 4; nt++) {
                const int rb = wn * 16 + nt * 32 + lrow;
                const int pb = (ks * 4 + quad + (rb & 7)) & 7;
                bf[nt] = *(const f16x8*)&Bs[rb * 64 + pb * 8];
            }
#pragma unroll
            for (int mt = 0; mt < 4; mt++)
#pragma unroll
                for (int nt = 0; nt < 4; nt++)
                    acc[mt][nt] = __builtin_amdgcn_mfma_f32_16x16x32_f16(af[mt], bf[nt], acc[mt][nt], 0, 0, 0);
        }
    }

    const int head = blockIdx.y;
    float bs_[4];
#pragma unroll
    for (int nt = 0; nt < 4; nt++) bs_[nt] = bias[n0 + nt * 32 + wn * 16 + lrow];
#pragma unroll
    for (int mt = 0; mt < 4; mt++) {
#pragma unroll
        for (int r = 0; r < 4; r++) {
            const int m  = m0 + wm * 64 + mt * 16 + quad * 4 + r;
            const int bb = m >> 11;
            const int st = m & (S_ - 1);
            float res[4];
#pragma unroll
            for (int nt = 0; nt < 4; nt++) res[nt] = acc[mt][nt][r] + bs_[nt];
            if (z < 2) {
                const float* cr = cosp + st * D_;
                const float* sr2 = sinp + st * D_;
#pragma unroll
                for (int pr = 0; pr < 2; pr++) {
                    const int dlo = pr * 32 + wn * 16 + lrow;
                    float cl = cr[dlo], sl = sr2[dlo], ch = cr[dlo + 64], sh = sr2[dlo + 64];
                    float lo = res[pr], hi = res[pr + 2];
                    res[pr]     = lo * cl - hi * sl;
                    res[pr + 2] = hi * ch + lo * sh;
                }
                half_t* dst = (z == 0 ? qo : ko) + ((size_t)(bb * NH + head) * S_ + st) * D_;
#pragma unroll
                for (int nt = 0; nt < 4; nt++) dst[nt * 32 + wn * 16 + lrow] = (half_t)res[nt];
            } else {
                half_t* dst = vto + (size_t)(bb * NH + head) * D_ * S_ + st;
#pragma unroll
                for (int nt = 0; nt < 4; nt++) dst[(size_t)(nt * 32 + wn * 16 + lrow) * S_] = (half_t)res[nt];
            }
        }
    }
}

// ---------------- flash attention: Q-tile 128 (wave owns 32 rows), S^T softmax ----------------
// T14 async-STAGE (reg-staged next K/V tile, loads in flight across compute) + T5 setprio.
// rs accumulation treed (depth 32 -> 6 dependent fadds).
#define PLD 72
__global__ __launch_bounds__(256, 2) void attn_kernel(
    const half_t* __restrict__ qb, const half_t* __restrict__ kb,
    const half_t* __restrict__ vtb, half_t* __restrict__ ob)
{
    __shared__ __align__(16) half_t ks[64 * 128];      // 16 KB swizzled
    __shared__ __align__(16) half_t vs[128 * 64];      // 16 KB swizzled
    __shared__ __align__(16) half_t ps[4 * 32 * PLD];  // 18 KB wave-private P (A-layout)
    const int head = blockIdx.y, b = blockIdx.z;
    const int bh = b * NH + head;
    const int tid = threadIdx.x, wave = tid >> 6, lane = tid & 63;
    const int quad = lane >> 4, lrow = lane & 15;
    // scale * log2(e): softmax computed in exp2 domain
    const float SC = 0.08838834764831845f * 1.4426950408889634f;
    const int q0 = blockIdx.x * 128 + wave * 32;

    // Q fragments, pre-scaled (used as MFMA *B* operand: B-frag(X) == A-frag(X) data)
    f16x8 qf[2][4];
#pragma unroll
    for (int mt = 0; mt < 2; mt++) {
        const half_t* qrow = qb + ((size_t)bh * S_ + q0 + mt * 16 + lrow) * D_;
#pragma unroll
        for (int kc = 0; kc < 4; kc++) {
            f16x8 v = *(const f16x8*)(qrow + kc * 32 + quad * 8);
#pragma unroll
            for (int j = 0; j < 8; j++) v[j] = (half_t)((float)v[j] * SC);
            qf[mt][kc] = v;
        }
    }

    const half_t* kbase = kb + (size_t)bh * S_ * D_;
    const half_t* vbase = vtb + (size_t)bh * D_ * S_;
    const int pbase = wave * 32 * PLD;

    f16x8 kreg[4], vreg[4];
    // per-stripe source addresses, EXACTLY mirroring the glds16 addressing they replace:
    // K stripe i: row rk = wave*16 + i*4 + (lane>>4), col = (((lane&15) - (rk&7))&15)*8
    // V stripe i: row rv = wave*32 + i*8 + (lane>>3), col = (((lane&7) - (rv&7))&7)*8
#define LOAD_TILE(kt_) do {                                                           \
    _Pragma("unroll")                                                                 \
    for (int i = 0; i < 4; i++) {                                                     \
        const int rk_ = wave * 16 + i * 4 + (lane >> 4);                              \
        const int ck_ = (((lane & 15) - (rk_ & 7)) & 15) * 8;                         \
        kreg[i] = *(const f16x8*)(kbase + (size_t)((kt_) * 64 + rk_) * D_ + ck_);     \
        const int rv_ = wave * 32 + i * 8 + (lane >> 3);                              \
        const int cv_ = (((lane & 7) - (rv_ & 7)) & 7) * 8;                           \
        vreg[i] = *(const f16x8*)(vbase + (size_t)rv_ * S_ + (kt_) * 64 + cv_);       \
    }                                                                                 \
} while (0)
#define WRITE_TILE() do {                                                             \
    _Pragma("unroll")                                                                 \
    for (int i = 0; i < 4; i++) {                                                     \
        *(f16x8*)&ks[(wave * 16 + i * 4) * 128 + lane * 8] = kreg[i];                 \
        *(f16x8*)&vs[(wave * 32 + i * 8) * 64  + lane * 8] = vreg[i];                 \
    }                                                                                 \
} while (0)

    float m_run[2] = {-1e30f, -1e30f}, l_run[2] = {0.f, 0.f};
    f32x4 o[2][8] = {};

    // prologue: tile 0 staged
    LOAD_TILE(0);
    WRITE_TILE();
    __syncthreads();

    for (int kt = 0; kt < 32; kt++) {
        // issue next tile's global loads now; they land during compute (T14)
        if (kt + 1 < 32) LOAD_TILE(kt + 1);

        // S^T = K_tile . Q^T : lane holds q-row = lrow, k-col = nt*16+quad*4+r  (in-lane!)
        f32x4 st[2][4] = {};
        __builtin_amdgcn_s_setprio(1);
#pragma unroll
        for (int nt = 0; nt < 4; nt++) {
            const int rk2 = nt * 16 + lrow;
#pragma unroll
            for (int kc = 0; kc < 4; kc++) {
                const int pk = (kc * 4 + quad + (rk2 & 7)) & 15;
                f16x8 kf = *(const f16x8*)&ks[rk2 * 128 + pk * 8];
                st[0][nt] = __builtin_amdgcn_mfma_f32_16x16x32_f16(kf, qf[0][kc], st[0][nt], 0, 0, 0);
                st[1][nt] = __builtin_amdgcn_mfma_f32_16x16x32_f16(kf, qf[1][kc], st[1][nt], 0, 0, 0);
            }
        }
        __builtin_amdgcn_s_setprio(0);

        // online softmax: in-lane tree + 2 shuffles; packed b64 P stores (A-layout)
        bool upd = false;
        float alpha[2];
#pragma unroll
        for (int mt = 0; mt < 2; mt++) {
            float m01 = fmaxf(fmaxf(st[mt][0][0], st[mt][0][1]), fmaxf(st[mt][0][2], st[mt][0][3]));
            float m11 = fmaxf(fmaxf(st[mt][1][0], st[mt][1][1]), fmaxf(st[mt][1][2], st[mt][1][3]));
            float m21 = fmaxf(fmaxf(st[mt][2][0], st[mt][2][1]), fmaxf(st[mt][2][2], st[mt][2][3]));
            float m31 = fmaxf(fmaxf(st[mt][3][0], st[mt][3][1]), fmaxf(st[mt][3][2], st[mt][3][3]));
            float mx = fmaxf(fmaxf(m01, m11), fmaxf(m21, m31));
            mx = fmaxf(mx, __shfl_xor(mx, 16));
            mx = fmaxf(mx, __shfl_xor(mx, 32));
            const float mnew = fmaxf(m_run[mt], mx);
            alpha[mt] = fexp2(m_run[mt] - mnew);
            upd = upd || (mnew > m_run[mt]);
            m_run[mt] = mnew;
            float rsp[4];
#pragma unroll
            for (int nt = 0; nt < 4; nt++) {
                f16x4_t pk4;
                float r0 = fexp2(st[mt][nt][0] - mnew);
                float r1 = fexp2(st[mt][nt][1] - mnew);
                float r2 = fexp2(st[mt][nt][2] - mnew);
                float r3 = fexp2(st[mt][nt][3] - mnew);
                pk4[0] = (half_t)r0; pk4[1] = (half_t)r1;
                pk4[2] = (half_t)r2; pk4[3] = (half_t)r3;
                rsp[nt] = (r0 + r1) + (r2 + r3);
                *(f16x4_t*)&ps[pbase + (mt * 16 + lrow) * PLD + nt * 16 + quad * 4] = pk4;
            }
            float rs = (rsp[0] + rsp[1]) + (rsp[2] + rsp[3]);
            rs += __shfl_xor(rs, 16);
            rs += __shfl_xor(rs, 32);
            l_run[mt] = l_run[mt] * alpha[mt] + rs;
        }
        if (__any(upd)) {
#pragma unroll
            for (int mt = 0; mt < 2; mt++) {
                float ab[4];
#pragma unroll
                for (int r = 0; r < 4; r++) ab[r] = __shfl(alpha[mt], quad * 4 + r, 16);
#pragma unroll
                for (int dt = 0; dt < 8; dt++)
#pragma unroll
                    for (int r = 0; r < 4; r++) o[mt][dt][r] *= ab[r];
            }
        }

        // O += P V
        __builtin_amdgcn_s_setprio(1);
#pragma unroll
        for (int kc2 = 0; kc2 < 2; kc2++) {
            f16x8 pf0 = *(const f16x8*)&ps[pbase + lrow * PLD + kc2 * 32 + quad * 8];
            f16x8 pf1 = *(const f16x8*)&ps[pbase + (16 + lrow) * PLD + kc2 * 32 + quad * 8];
#pragma unroll
            for (int dt = 0; dt < 8; dt++) {
                const int rv2 = dt * 16 + lrow;
                const int pv = (kc2 * 4 + quad + (rv2 & 7)) & 7;
                f16x8 vf = *(const f16x8*)&vs[rv2 * 64 + pv * 8];
                o[0][dt] = __builtin_amdgcn_mfma_f32_16x16x32_f16(pf0, vf, o[0][dt], 0, 0, 0);
                o[1][dt] = __builtin_amdgcn_mfma_f32_16x16x32_f16(pf1, vf, o[1][dt], 0, 0, 0);
            }
        }
        __builtin_amdgcn_s_setprio(0);

        // stage next tile into LDS (loads have had the whole compute to land)
        __syncthreads();
        if (kt + 1 < 32) WRITE_TILE();
        __syncthreads();
    }

    // epilogue
#pragma unroll
    for (int mt = 0; mt < 2; mt++) {
        const float rl = 1.f / l_run[mt];
        float rb[4];
#pragma unroll
        for (int r = 0; r < 4; r++) rb[r] = __shfl(rl, quad * 4 + r, 16);
#pragma unroll
        for (int dt = 0; dt < 8; dt++) {
            const int d = dt * 16 + lrow;
#pragma unroll
            for (int r = 0; r < 4; r++) {
                const int row = q0 + mt * 16 + quad * 4 + r;
                ob[((size_t)b * S_ + row) * HID + head * D_ + d] = (half_t)(o[mt][dt][r] * rb[r]);
            }
        }
    }
#undef LOAD_TILE
#undef WRITE_TILE
}

// ---------------- output projection (exact R0 form: 128x128, BK=32) ----------------
// Reverted to the R0 baseline version (rest-era 259-270us); BK64/BM64 variants both
// coexisted with rest ~291-302 -> single-variable A/B this round.
__global__ __launch_bounds__(256, 3) void out_gemm(
    const half_t* __restrict__ ab, const half_t* __restrict__ wob, float* __restrict__ out)
{
    __shared__ __align__(16) half_t As[128 * 32];
    __shared__ __align__(16) half_t Bs[128 * 32];
    const int m0 = blockIdx.x * 128;
    const int n0 = blockIdx.y * 128;
    const int tid = threadIdx.x, wave = tid >> 6, lane = tid & 63;
    const int quad = lane >> 4, lrow = lane & 15;
    const int wm = wave >> 1, wn = wave & 1;

    const int r0 = wave * 32 + (lane >> 2);
    const int r1 = r0 + 16;
    const int c0 = (((lane & 3) - (r0 >> 1)) & 3) * 8;
    const int c1 = (((lane & 3) - (r1 >> 1)) & 3) * 8;
    const half_t* ag0 = ab  + (size_t)(m0 + r0) * HID + c0;
    const half_t* ag1 = ab  + (size_t)(m0 + r1) * HID + c1;
    const half_t* bg0 = wob + (size_t)(n0 + r0) * HID + c0;
    const half_t* bg1 = wob + (size_t)(n0 + r1) * HID + c1;
    half_t* al0 = &As[(wave * 32) * 32];
    half_t* al1 = &As[(wave * 32 + 16) * 32];
    half_t* bl0 = &Bs[(wave * 32) * 32];
    half_t* bl1 = &Bs[(wave * 32 + 16) * 32];

    f32x4 acc[4][4] = {};

    for (int k0 = 0; k0 < HID; k0 += 32) {
        __syncthreads();
        glds16(ag0 + k0, al0);
        glds16(ag1 + k0, al1);
        glds16(bg0 + k0, bl0);
        glds16(bg1 + k0, bl1);
        __syncthreads();
        f16x8 af[4], bf[4];
#pragma unroll
        for (int mt = 0; mt < 4; mt++) {
            const int ra = wm * 64 + mt * 16 + lrow;
            const int pa = (quad + (ra >> 1)) & 3;
            af[mt] = *(const f16x8*)&As[ra * 32 + pa * 8];
        }
#pragma unroll
        for (int nt = 0; nt < 4; nt++) {
            const int rb = wn * 16 + nt * 32 + lrow;
            const int pb = (quad + (rb >> 1)) & 3;
            bf[nt] = *(const f16x8*)&Bs[rb * 32 + pb * 8];
        }
#pragma unroll
        for (int mt = 0; mt < 4; mt++)
#pragma unroll
            for (int nt = 0; nt < 4; nt++)
                acc[mt][nt] = __builtin_amdgcn_mfma_f32_16x16x32_f16(af[mt], bf[nt], acc[mt][nt], 0, 0, 0);
    }

#pragma unroll
    for (int mt = 0; mt < 4; mt++)
#pragma unroll
        for (int r = 0; r < 4; r++) {
            const int m = m0 + wm * 64 + mt * 16 + quad * 4 + r;
#pragma unroll
            for (int nt = 0; nt < 4; nt++)
                out[(size_t)m * HID + n0 + nt * 32 + wn * 16 + lrow] = acc[mt][nt][r];
        }
}

extern "C" void kernel_launch(void* const* d_in, const int* in_sizes, int n_in,
                              void* d_out, int out_size, void* d_ws, size_t ws_size,
                              hipStream_t stream)
{
    const float* x    = (const float*)d_in[0];
    const float* cosp = (const float*)d_in[1];
    const float* sinp = (const float*)d_in[2];
    const float* wq   = (const float*)d_in[3];
    const float* bq   = (const float*)d_in[4];
    const float* wk   = (const float*)d_in[5];
    const float* bk   = (const float*)d_in[6];
    const float* wv   = (const float*)d_in[7];
    const float* bv   = (const float*)d_in[8];
    const float* wo   = (const float*)d_in[9];
    float* out = (float*)d_out;

    half_t* w   = (half_t*)d_ws;
    half_t* xb  = w;
    half_t* wqb = xb  + 8388608;
    half_t* wkb = wqb + 4194304;
    half_t* wvb = wkb + 4194304;
    half_t* wob = wvb + 4194304;
    half_t* qo  = wob + 4194304;        // (b,h,s,d)
    half_t* ko  = qo  + 8388608;        // (b,h,s,d)
    half_t* vto = ko  + 8388608;        // (b,h,d,s)
    half_t* ob  = vto + 8388608;        // (b,s,h*d)

    cvt_all<<<24576, 256, 0, stream>>>(x, wq, wk, wv, wo, xb);
    qkv_gemm<<<dim3(32, 16, 3), 256, 0, stream>>>(xb, wqb, wkb, wvb, bq, bk, bv,
                                                  cosp, sinp, qo, ko, vto);
    attn_kernel<<<dim3(16, 16, 2), 256, 0, stream>>>(qo, ko, vto, ob);
    out_gemm<<<dim3(32, 16), 256, 0, stream>>>(ob, wob, out);
}